// Round 17
// baseline (37.314 us; speedup 1.0000x reference)
//
#include <hip/hip_runtime.h>
#include <hip/hip_fp16.h>
#include <math.h>

// T=24, NSEQ=16384, FS=64, FM=16, FC=16 -> I=96; H=32.
//
// R17 = R14 with TWO independent 16-seq recurrences per consumer wave
// (software ILP: weights shared in regs, only state duplicated; the two
// chains interleave at compile time and cover each other's stalls).
//  - block = 128 thr: wave0 = CONSUMER (2 groups x 32 units, in-register
//    sigma recurrence), wave1 = PRODUCER (xacc tiles for both groups).
//  - 512 blocks x 32 seqs; LDS [2buf][2grp][6tile][16][20]f32 = 60 KB
//    -> 2 blocks/CU; 1024 waves = 1/SIMD (consumer SIMDs run 2-way ILP).
//  - Gate math / sigma layout / direct weight gather / lgkm-only barrier:
//    bit-identical to R14 (best measured, absmax 0.0625).

typedef __attribute__((ext_vector_type(8))) _Float16 half8;
typedef __attribute__((ext_vector_type(4))) float f32x4;
typedef __attribute__((ext_vector_type(4))) unsigned int uix4;

#define NSEQ 16384
#define TSTEPS 24
#define LOG2E 1.44269504088896340736f

__device__ __forceinline__ float exp2_fast(float x) {
#if __has_builtin(__builtin_amdgcn_exp2f)
  return __builtin_amdgcn_exp2f(x);
#else
  return __expf(x * 0.6931471805599453f);
#endif
}

__device__ __forceinline__ unsigned int pk_f16(float a, float b) {
#if __has_builtin(__builtin_amdgcn_cvt_pkrtz)
  auto r = __builtin_amdgcn_cvt_pkrtz(a, b);
  return __builtin_bit_cast(unsigned int, r);
#else
  return (unsigned)__half_as_ushort(__float2half(a)) |
         ((unsigned)__half_as_ushort(__float2half(b)) << 16);
#endif
}
__device__ __forceinline__ unsigned int pk_f16_rn(float a, float b) {
  return (unsigned)__half_as_ushort(__float2half(a)) |
         ((unsigned)__half_as_ushort(__float2half(b)) << 16);
}
__device__ __forceinline__ half8 mk_h8(unsigned int a, unsigned int b,
                                       unsigned int c, unsigned int d) {
  uix4 v = {a, b, c, d};
  return __builtin_bit_cast(half8, v);
}
__device__ __forceinline__ f32x4 mfma_h(half8 a, half8 b, f32x4 c) {
  return __builtin_amdgcn_mfma_f32_16x16x32_f16(a, b, c, 0, 0, 0);
}

// workgroup barrier draining LDS ops only
__device__ __forceinline__ void barrier_lds() {
  asm volatile("s_waitcnt lgkmcnt(0)" ::: "memory");
  __builtin_amdgcn_s_barrier();
}

__global__ __launch_bounds__(128)
void gru13(const float* __restrict__ spatial,
           const float* __restrict__ met,
           const float* __restrict__ ctx,
           const float* __restrict__ W_ih,
           const float* __restrict__ W_hh,
           const float* __restrict__ b_ih,
           const float* __restrict__ b_hh,
           const float* __restrict__ Wp,
           float* __restrict__ out) {
  // [buf][grp][tile j][seq 16][20-pad f32] = 60 KB
  __shared__ float xls[2][2][6][16][20];

  const int tid = threadIdx.x;
  const int lane = tid & 63;
  const int wv = tid >> 6;         // 0 = consumer, 1 = producer
  const int l15 = lane & 15;
  const int c = lane >> 4;         // 0..3
  const int seq0 = blockIdx.x * 32 + l15;        // group 0
  const int seq1 = seq0 + 16;                    // group 1
  const f32x4 zero4 = {0.f, 0.f, 0.f, 0.f};

  if (wv == 1) {
    // ======================= PRODUCER (both groups) =======================
    half8 wmc[6];
    f32x4 acc_i[2][6];
#pragma unroll
    for (int j = 0; j < 6; ++j) {
      const float sc = (j < 4) ? LOG2E : (2.0f * LOG2E);
      const float* mr = W_ih + (size_t)(j * 16 + l15) * 96 + 64 + c * 8;
      float4 wa = *(const float4*)mr;
      float4 wb = *(const float4*)(mr + 4);
      wmc[j] = mk_h8(pk_f16_rn(wa.x * sc, wa.y * sc),
                     pk_f16_rn(wa.z * sc, wa.w * sc),
                     pk_f16_rn(wb.x * sc, wb.y * sc),
                     pk_f16_rn(wb.z * sc, wb.w * sc));
      const int rowb = j * 16 + 4 * c;
      float4 vih = *(const float4*)(b_ih + rowb);
      float bv0, bv1, bv2, bv3;
      if (j < 4) {
        float4 vhh = *(const float4*)(b_hh + rowb);
        bv0 = (vih.x + vhh.x) * sc; bv1 = (vih.y + vhh.y) * sc;
        bv2 = (vih.z + vhh.z) * sc; bv3 = (vih.w + vhh.w) * sc;
      } else {
        bv0 = vih.x * sc; bv1 = vih.y * sc; bv2 = vih.z * sc; bv3 = vih.w * sc;
      }
#pragma unroll
      for (int g = 0; g < 2; ++g) {
        acc_i[g][j][0] = bv0; acc_i[g][j][1] = bv1;
        acc_i[g][j][2] = bv2; acc_i[g][j][3] = bv3;
      }
    }
    // fold spatial (time-invariant), per group
#pragma unroll
    for (int g = 0; g < 2; ++g) {
      const int seqg = g ? seq1 : seq0;
#pragma unroll
      for (int kt = 0; kt < 2; ++kt) {
        const float* sp = spatial + (size_t)seqg * 64 + kt * 32 + c * 8;
        float4 a0 = *(const float4*)sp;
        float4 a1 = *(const float4*)(sp + 4);
        half8 sf = mk_h8(pk_f16(a0.x, a0.y), pk_f16(a0.z, a0.w),
                         pk_f16(a1.x, a1.y), pk_f16(a1.z, a1.w));
#pragma unroll
        for (int j = 0; j < 6; ++j) {
          const float sc = (j < 4) ? LOG2E : (2.0f * LOG2E);
          const float* wr = W_ih + (size_t)(j * 16 + l15) * 96 + kt * 32 + c * 8;
          float4 wa = *(const float4*)wr;
          float4 wb = *(const float4*)(wr + 4);
          half8 wsp = mk_h8(pk_f16_rn(wa.x * sc, wa.y * sc),
                            pk_f16_rn(wa.z * sc, wa.w * sc),
                            pk_f16_rn(wb.x * sc, wb.y * sc),
                            pk_f16_rn(wb.z * sc, wb.w * sc));
          acc_i[g][j] = mfma_h(wsp, sf, acc_i[g][j]);
        }
      }
    }
    const float* lp0 = ((c < 2) ? met : ctx) + (size_t)seq0 * 16 + (c & 1) * 8;
    const float* lp1 = ((c < 2) ? met : ctx) + (size_t)seq1 * 16 + (c & 1) * 8;

    // xacc(0) -> buffer 0, both groups
#pragma unroll
    for (int g = 0; g < 2; ++g) {
      const float* lp = g ? lp1 : lp0;
      float4 a0 = *(const float4*)lp;
      float4 a1 = *(const float4*)(lp + 4);
      half8 xf = mk_h8(pk_f16(a0.x, a0.y), pk_f16(a0.z, a0.w),
                       pk_f16(a1.x, a1.y), pk_f16(a1.z, a1.w));
#pragma unroll
      for (int j = 0; j < 6; ++j) {
        f32x4 D = mfma_h(wmc[j], xf, acc_i[g][j]);
        *(f32x4*)&xls[0][g][j][l15][c * 4] = D;
      }
    }
    // parity slots per group: slot s holds x(t+1) for step t with t&1==s
    float4 s00a = *(const float4*)(lp0 + (size_t)1 * NSEQ * 16);
    float4 s00b = *(const float4*)(lp0 + (size_t)1 * NSEQ * 16 + 4);
    float4 s01a = *(const float4*)(lp0 + (size_t)2 * NSEQ * 16);
    float4 s01b = *(const float4*)(lp0 + (size_t)2 * NSEQ * 16 + 4);
    float4 s10a = *(const float4*)(lp1 + (size_t)1 * NSEQ * 16);
    float4 s10b = *(const float4*)(lp1 + (size_t)1 * NSEQ * 16 + 4);
    float4 s11a = *(const float4*)(lp1 + (size_t)2 * NSEQ * 16);
    float4 s11b = *(const float4*)(lp1 + (size_t)2 * NSEQ * 16 + 4);

    barrier_lds();

#pragma unroll 2
    for (int t = 0; t < TSTEPS; ++t) {
      const int buf = (t + 1) & 1;
      const int tf = (t + 3 < TSTEPS) ? (t + 3) : (TSTEPS - 1);
      {  // group 0
        float4 xa = (t & 1) ? s01a : s00a;
        float4 xb = (t & 1) ? s01b : s00b;
        half8 xf = mk_h8(pk_f16(xa.x, xa.y), pk_f16(xa.z, xa.w),
                         pk_f16(xb.x, xb.y), pk_f16(xb.z, xb.w));
#pragma unroll
        for (int j = 0; j < 6; ++j) {
          f32x4 D = mfma_h(wmc[j], xf, acc_i[0][j]);
          *(f32x4*)&xls[buf][0][j][l15][c * 4] = D;
        }
        float4 na = *(const float4*)(lp0 + (size_t)tf * NSEQ * 16);
        float4 nb = *(const float4*)(lp0 + (size_t)tf * NSEQ * 16 + 4);
        if (t & 1) { s01a = na; s01b = nb; } else { s00a = na; s00b = nb; }
      }
      {  // group 1
        float4 xa = (t & 1) ? s11a : s10a;
        float4 xb = (t & 1) ? s11b : s10b;
        half8 xf = mk_h8(pk_f16(xa.x, xa.y), pk_f16(xa.z, xa.w),
                         pk_f16(xb.x, xb.y), pk_f16(xb.z, xb.w));
#pragma unroll
        for (int j = 0; j < 6; ++j) {
          f32x4 D = mfma_h(wmc[j], xf, acc_i[1][j]);
          *(f32x4*)&xls[buf][1][j][l15][c * 4] = D;
        }
        float4 na = *(const float4*)(lp1 + (size_t)tf * NSEQ * 16);
        float4 nb = *(const float4*)(lp1 + (size_t)tf * NSEQ * 16 + 4);
        if (t & 1) { s11a = na; s11b = nb; } else { s10a = na; s10b = nb; }
      }
      barrier_lds();
    }
    // producer done
  } else {
    // ================= CONSUMER (2 independent recurrences) =================
    __builtin_amdgcn_s_setprio(1);
    half8 whh[6];
#pragma unroll
    for (int j = 0; j < 6; ++j) {
      const float sc = (j < 4) ? LOG2E : (2.0f * LOG2E);
      const float* wr = W_hh + (size_t)(j * 16 + l15) * 32;
      float4 a = *(const float4*)(wr + 4 * c);
      float4 b = *(const float4*)(wr + 16 + 4 * c);
      whh[j] = mk_h8(pk_f16_rn(a.x * sc, a.y * sc),
                     pk_f16_rn(a.z * sc, a.w * sc),
                     pk_f16_rn(b.x * sc, b.y * sc),
                     pk_f16_rn(b.z * sc, b.w * sc));
    }
    f32x4 bhnA, bhnB;
    {
      float4 va = *(const float4*)(b_hh + 64 + 4 * c);
      float4 vb = *(const float4*)(b_hh + 64 + 16 + 4 * c);
      bhnA[0] = 2.0f * LOG2E * va.x; bhnA[1] = 2.0f * LOG2E * va.y;
      bhnA[2] = 2.0f * LOG2E * va.z; bhnA[3] = 2.0f * LOG2E * va.w;
      bhnB[0] = 2.0f * LOG2E * vb.x; bhnB[1] = 2.0f * LOG2E * vb.y;
      bhnB[2] = 2.0f * LOG2E * vb.z; bhnB[3] = 2.0f * LOG2E * vb.w;
    }
    float hstA[8], hstB[8];
#pragma unroll
    for (int i = 0; i < 8; ++i) { hstA[i] = 0.0f; hstB[i] = 0.0f; }
    half8 fhA = mk_h8(0u, 0u, 0u, 0u);
    half8 fhB = mk_h8(0u, 0u, 0u, 0u);

    barrier_lds();

#pragma unroll 2
    for (int t = 0; t < TSTEPS; ++t) {
      const int buf = t & 1;
      // group A tiles
      f32x4 a0 = *(const f32x4*)&xls[buf][0][0][l15][c * 4];
      f32x4 a1 = *(const f32x4*)&xls[buf][0][1][l15][c * 4];
      f32x4 a2 = *(const f32x4*)&xls[buf][0][2][l15][c * 4];
      f32x4 a3 = *(const f32x4*)&xls[buf][0][3][l15][c * 4];
      f32x4 a4 = *(const f32x4*)&xls[buf][0][4][l15][c * 4];
      f32x4 a5 = *(const f32x4*)&xls[buf][0][5][l15][c * 4];
      // group B tiles
      f32x4 b0 = *(const f32x4*)&xls[buf][1][0][l15][c * 4];
      f32x4 b1 = *(const f32x4*)&xls[buf][1][1][l15][c * 4];
      f32x4 b2 = *(const f32x4*)&xls[buf][1][2][l15][c * 4];
      f32x4 b3 = *(const f32x4*)&xls[buf][1][3][l15][c * 4];
      f32x4 b4 = *(const f32x4*)&xls[buf][1][4][l15][c * 4];
      f32x4 b5 = *(const f32x4*)&xls[buf][1][5][l15][c * 4];

      // 12 MFMAs, two independent chains (A and B interleave freely)
      f32x4 Adr0 = mfma_h(whh[0], fhA, a0);
      f32x4 Bdr0 = mfma_h(whh[0], fhB, b0);
      f32x4 Adr1 = mfma_h(whh[1], fhA, a1);
      f32x4 Bdr1 = mfma_h(whh[1], fhB, b1);
      f32x4 Adz0 = mfma_h(whh[2], fhA, a2);
      f32x4 Bdz0 = mfma_h(whh[2], fhB, b2);
      f32x4 Adz1 = mfma_h(whh[3], fhA, a3);
      f32x4 Bdz1 = mfma_h(whh[3], fhB, b3);
      f32x4 Ath0 = mfma_h(whh[4], fhA, bhnA);
      f32x4 Bth0 = mfma_h(whh[4], fhB, bhnA);
      f32x4 Ath1 = mfma_h(whh[5], fhA, bhnB);
      f32x4 Bth1 = mfma_h(whh[5], fhB, bhnB);

      // gates (R14 merged-rcp form), both groups
      float hvA[8], hvB[8];
#pragma unroll
      for (int jj = 0; jj < 2; ++jj) {
        f32x4 Addr = jj ? Adr1 : Adr0;  f32x4 Bddr = jj ? Bdr1 : Bdr0;
        f32x4 Addz = jj ? Adz1 : Adz0;  f32x4 Bddz = jj ? Bdz1 : Bdz0;
        f32x4 Atth = jj ? Ath1 : Ath0;  f32x4 Btth = jj ? Bth1 : Bth0;
        f32x4 Atti = jj ? a5 : a4;      f32x4 Btti = jj ? b5 : b4;
#pragma unroll
        for (int q = 0; q < 4; ++q) {
          const int i = jj * 4 + q;
          {
            float R = exp2_fast(-Addr[q]);
            float r = __builtin_amdgcn_rcpf(1.0f + R);
            float E = fminf(exp2_fast(-Addz[q]), 1e30f);
            float Y = fmaf(r, Atth[q], Atti[q]);
            float e = fminf(exp2_fast(-Y), 1e30f);
            float oe = 1.0f + e, oE = 1.0f + E;
            float inv = __builtin_amdgcn_rcpf(oE * oe);
            float num = fmaf(hstA[i], oe, fmaf(-E, e, E));
            float hv = num * inv;
            hstA[i] = hv; hvA[i] = hv;
          }
          {
            float R = exp2_fast(-Bddr[q]);
            float r = __builtin_amdgcn_rcpf(1.0f + R);
            float E = fminf(exp2_fast(-Bddz[q]), 1e30f);
            float Y = fmaf(r, Btth[q], Btti[q]);
            float e = fminf(exp2_fast(-Y), 1e30f);
            float oe = 1.0f + e, oE = 1.0f + E;
            float inv = __builtin_amdgcn_rcpf(oE * oe);
            float num = fmaf(hstB[i], oe, fmaf(-E, e, E));
            float hv = num * inv;
            hstB[i] = hv; hvB[i] = hv;
          }
        }
      }
      fhA = mk_h8(pk_f16(hvA[0], hvA[1]), pk_f16(hvA[2], hvA[3]),
                  pk_f16(hvA[4], hvA[5]), pk_f16(hvA[6], hvA[7]));
      fhB = mk_h8(pk_f16(hvB[0], hvB[1]), pk_f16(hvB[2], hvB[3]),
                  pk_f16(hvB[4], hvB[5]), pk_f16(hvB[6], hvB[7]));

      barrier_lds();
    }

    // ---- projection: both groups, 4 f-tiles each (Wp sigma-gathered) ----
#pragma unroll
    for (int pt = 0; pt < 4; ++pt) {
      const int frow = pt * 16 + l15;
      const float* wpb = Wp + frow;
      float v[8];
#pragma unroll
      for (int e = 0; e < 8; ++e) {
        int col = (e < 4) ? (4 * c + e) : (16 + 4 * c + (e - 4));
        v[e] = wpb[(size_t)col * 64];
      }
      unsigned int uh[4], ul[4];
#pragma unroll
      for (int e2 = 0; e2 < 4; ++e2) {
        float va = v[2 * e2], vb = v[2 * e2 + 1];
        __half ha = __float2half(va), hb = __float2half(vb);
        float la = va - __half2float(ha), lb = vb - __half2float(hb);
        uh[e2] = (unsigned)__half_as_ushort(ha) |
                 ((unsigned)__half_as_ushort(hb) << 16);
        ul[e2] = pk_f16_rn(la, lb);
      }
      half8 wph = mk_h8(uh[0], uh[1], uh[2], uh[3]);
      half8 wpl = mk_h8(ul[0], ul[1], ul[2], ul[3]);
      f32x4 oA = mfma_h(wph, fhA, zero4);
      oA = mfma_h(wpl, fhA, oA);
      f32x4 oB = mfma_h(wph, fhB, zero4);
      oB = mfma_h(wpl, fhB, oB);
      float* opA = out + (size_t)seq0 * 64 + pt * 16 + 4 * c;
      *(float4*)opA = make_float4(oA[0], oA[1], oA[2], oA[3]);
      float* opB = out + (size_t)seq1 * 64 + pt * 16 + 4 * c;
      *(float4*)opB = make_float4(oB[0], oB[1], oB[2], oB[3]);
    }
    __builtin_amdgcn_s_setprio(0);
  }
}

extern "C" void kernel_launch(void* const* d_in, const int* in_sizes, int n_in,
                              void* d_out, int out_size, void* d_ws, size_t ws_size,
                              hipStream_t stream) {
  const float* spatial = (const float*)d_in[0];
  const float* met     = (const float*)d_in[1];
  const float* ctx     = (const float*)d_in[2];
  const float* W_ih    = (const float*)d_in[3];
  const float* W_hh    = (const float*)d_in[4];
  const float* b_ih    = (const float*)d_in[5];
  const float* b_hh    = (const float*)d_in[6];
  const float* Wp      = (const float*)d_in[7];
  float* out = (float*)d_out;

  hipLaunchKernelGGL(gru13, dim3(512), dim3(128), 0, stream,
                     spatial, met, ctx, W_ih, W_hh, b_ih, b_hh, Wp, out);
}